// Round 6
// baseline (272.369 us; speedup 1.0000x reference)
//
#include <hip/hip_runtime.h>

typedef __attribute__((ext_vector_type(8))) short bf16x8;   // 8 bf16 (4 VGPRs)
typedef __attribute__((ext_vector_type(4))) float f32x4;    // MFMA C/D
typedef unsigned short u16;
typedef unsigned int u32;

#define NLOG2E -1.44269504088896f   // -log2(e)
#define LOG2E   1.44269504088896f
#define SLICE 32768                 // one stats slice (32768 rows/cols total)

__device__ __forceinline__ float bf2f(u16 x) {
  union { u32 u; float f; } v; v.u = ((u32)x) << 16; return v.f;
}
__device__ __forceinline__ u16 f2b(float f) {
  union { float f; u32 u; } v; v.f = f;
  return (u16)((v.u + 0x7FFFu + ((v.u >> 16) & 1u)) >> 16);
}
// pack two fp32 -> one u32 of two bf16 (RNE), pure register ops (no alloca)
__device__ __forceinline__ u32 pk2(float lo, float hi) {
  return (u32)f2b(lo) | ((u32)f2b(hi) << 16);
}
// q_mask all ones: fp32 word0 = 0x3F800000, packed-bf16 word0 = 0x3F803F80
__device__ __forceinline__ bool inputs_are_bf16(const void* qmask) {
  return *(const u32*)qmask == 0x3F803F80u;
}

// fp32->bf16 convert, round-2 proven form (52-56us for 200MB; best of 3 measured
// variants): 4 consecutive float4 per thread, batched loads (MLP=4, VGPR=20).
// Lane-stride 64B is an L1 illusion: a wave's 4 instructions fully consume the
// same cache lines -> no HBM-level over-fetch. R3/R4 lesson: grid-stride loops
// and wider batches both get re-serialized by the compiler and run SLOWER.
__device__ __forceinline__ void convert16(const void* __restrict__ src,
                                          u16* __restrict__ dst, int idx) {
  const float4* s = (const float4*)src + (size_t)idx * 4;
  float4 v0 = s[0], v1 = s[1], v2 = s[2], v3 = s[3];
  uint4* d = (uint4*)dst + (size_t)idx * 2;
  uint4 w0, w1;
  w0.x = pk2(v0.x, v0.y); w0.y = pk2(v0.z, v0.w);
  w0.z = pk2(v1.x, v1.y); w0.w = pk2(v1.z, v1.w);
  w1.x = pk2(v2.x, v2.y); w1.y = pk2(v2.z, v2.w);
  w1.z = pk2(v3.x, v3.y); w1.w = pk2(v3.z, v3.w);
  d[0] = w0;
  d[1] = w1;
}

// ---------------- prep: U transpose + out zero ONLY (64 blocks, ~4 us).
// q/a conversion now lives entirely inside gemm_bt<0,1>'s grid (q is consumed
// there via inline fp32 staging; qb/ab are produced by its convert blocks).
__global__ __launch_bounds__(256) void prep_all(
    const void* __restrict__ q, const void* __restrict__ a,
    const void* __restrict__ U, const void* __restrict__ qmask,
    u16* __restrict__ qb, u16* __restrict__ ab, u16* __restrict__ Ut,
    float* __restrict__ out)
{
  const bool bf = inputs_are_bf16(qmask);
  const int t = threadIdx.x;
  const int bb = blockIdx.x;                      // [0,64)
  out[bb * 512 + t] = 0.f;                        // zero d_out (partial atomicAdds)
  out[bb * 512 + 256 + t] = 0.f;
  __shared__ u16 tile[64][65];
  const int bx = bb & 7, by = bb >> 3;
  #pragma unroll
  for (int i = 0; i < 16; i++) {
    int r = i * 4 + (t >> 6);
    int c = t & 63;
    size_t gi = (size_t)(by * 64 + r) * 512 + bx * 64 + c;
    tile[c][r] = bf ? ((const u16*)U)[gi] : f2b(((const float*)U)[gi]);
  }
  __syncthreads();
  #pragma unroll
  for (int i = 0; i < 16; i++) {
    int r = i * 4 + (t >> 6);
    int c = t & 63;
    Ut[(size_t)(bx * 64 + r) * 512 + by * 64 + c] = tile[r][c];
  }
}

// ---------------- 128x128 bf16 MFMA GEMM, C = A * B^T ----------------------------------
// Ring of 3 LDS buffers (48 KB + 1 KB masks -> 3 blocks/CU). B staged via
// global_load_lds width=16. 2-bit XOR swizzle slot = lq ^ ((row>>1)&3).
// AFP32==1 (gemm<0> fp32 main path): A is staged from fp32 q with INLINE convert:
//   per stage/wave: 2 B-gload_lds + 4 coalesced float4 loads (6 vmem ops) into one
//   of 3 named register sets (full unroll -> compile-time indices, no scratch);
//   steady gate "s_waitcnt vmcnt(12)" = 2 stages in flight; then pk2 + 2x
//   ds_write_b128 (just-in-time A), lgkmcnt(0)+barrier publishes A+B, MFMA, end
//   barrier fences buffer reuse (writeA(t+1)->buf (t+1)%3 last read at t-2;
//   B-gload(t+3)->buf t%3 read this iter). This removes prep's 27us serial
//   q-convert from the critical path. Extra grid blocks (y>=256): 8192 convert
//   blocks producing qb (for partial) and ab (for gemm<1>), overlapped with GEMM.
// AFP32==0: original gload_lds A-staging (bf16 ws or alias), gates vmcnt 8/4/0.
// EPI==1 only: XCD remap (2-col x 4-row region per XCD) + mask-penalty acc init +
//   fused sigmoid/exp epilogue with private-slice stats (no atomics).
template<int EPI, int AFP32>
__global__ __launch_bounds__(256, 3) void gemm_bt(
    const u16* __restrict__ A, const u16* __restrict__ B,
    u16* __restrict__ C, float scaleC,
    size_t strideA, size_t strideB,
    const void* __restrict__ q_mask, const void* __restrict__ a_mask,
    float* __restrict__ statsP,
    const u16* __restrict__ A_alias, const u16* __restrict__ B_alias,
    const void* __restrict__ convQ_src, u16* __restrict__ convQ_dst,
    const void* __restrict__ convA_src, u16* __restrict__ convA_dst,
    const float* __restrict__ Af32)
{
  if constexpr (EPI == 0 && AFP32 == 1) {
    if (blockIdx.y >= 256) {
      // fused convert blocks: cid<4096 -> q->qb, else a->ab (inputs fp32 by host select)
      const int cid = (blockIdx.y - 256) * 4 + blockIdx.x;   // [0, 8192)
      const int idx = (cid & 4095) * 256 + (int)threadIdx.x; // [0, 1048576)
      if (cid < 4096) convert16(convQ_src, convQ_dst, idx);
      else            convert16(convA_src, convA_dst, idx);
      return;
    }
  }

  __shared__ __align__(16) char smem[50176];
  // ring buf i at smem + i*16384: A 8 KB (128 rows x 32 K, 64 B/row) then B 8 KB
  u16* Ct  = (u16*)smem;                 // 128x144 u16 = 36864 B (EPI=0 epilogue, reuse)
  float* redS = (float*)smem;            // 128x33 f32 = 16896 B (EPI=1 epilogue, reuse)
  float* redM = (float*)(smem + 16896);  // 128x33 f32 (post-loop only)
  float* colS = (float*)(smem + 33792);  // 128x2 f32: col sums per wr half
  float* colM = (float*)(smem + 34816);  // 128x2 f32: col mins per wr half
  float* qp = (float*)(smem + 49152);    // 128 f32 penalties
  float* ap = (float*)(smem + 49664);    // 128 f32

  int bx = blockIdx.x, by = blockIdx.y;
  const int bz = blockIdx.z;
  if (EPI) {
    // XCD clustering: k = blockIdx.x is the XCD (flat%8); slot s = blockIdx.y.
    const int k = blockIdx.x, s = blockIdx.y;
    bx = (k & 3) * 2 + (s & 1);
    by = (k >> 2) * 4 + (s >> 1);
  }
  const int tid  = threadIdx.x;
  const int lane = tid & 63;
  const int wave = tid >> 6;
  const int wr = wave >> 1, wc = wave & 1;   // 2x2 wave grid, 64x64 each
  const int l15 = lane & 15, lq = lane >> 4; // lane-in-16, quad

  const bool bfin = inputs_are_bf16(q_mask);
  const u16* Asel = (bfin && A_alias) ? A_alias : A;
  const u16* Bsel = (bfin && B_alias) ? B_alias : B;

  // staging lane map: row_local = lane>>2, phys slot = lane&3,
  // logical chunk = slot ^ ((row>>1)&3) -> (lane&3) ^ ((lane>>3)&3)
  const int srl  = lane >> 2;
  const int sc   = (lane & 3) ^ ((lane >> 3) & 3);
  const size_t sgo = (size_t)srl * 512 + sc * 8;   // per-lane elem offset within a stage
  // fragment read: phys slot = lq ^ ((arow>>1)&3) -> lane-constant
  const int foff = ((lq ^ ((l15 >> 1) & 3)) * 8);

  const u16* Ab = Asel + strideA * bz + (size_t)by * 128 * 512;
  const u16* Bb = Bsel + strideB * bz + (size_t)bx * 128 * 512;

  if (EPI) {
    if (tid < 128) {
      int gi = bz * 1024 + by * 128 + tid;
      float v = bfin ? bf2f(((const u16*)q_mask)[gi]) : ((const float*)q_mask)[gi];
      qp[tid] = (v > 0.f) ? 0.f : 1e30f;
    } else {
      int gj = bz * 1024 + bx * 128 + (tid - 128);
      float v = bfin ? bf2f(((const u16*)a_mask)[gj]) : ((const float*)a_mask)[gj];
      ap[tid - 128] = (v > 0.f) ? 0.f : 1e30f;
    }
    __syncthreads();   // drains mask loads before any K-loop staging
  }

  f32x4 acc[4][4];
  if (EPI) {
    #pragma unroll
    for (int mt = 0; mt < 4; mt++)
      #pragma unroll
      for (int nt = 0; nt < 4; nt++) {
        float cp = ap[wc * 64 + nt * 16 + l15];
        #pragma unroll
        for (int r = 0; r < 4; r++)
          acc[mt][nt][r] = qp[wr * 64 + mt * 16 + lq * 4 + r] + cp;
      }
  } else {
    #pragma unroll
    for (int i = 0; i < 4; i++)
      #pragma unroll
      for (int j = 0; j < 4; j++) {
        f32x4 z = {0.f, 0.f, 0.f, 0.f};
        acc[i][j] = z;
      }
  }

  // B-half staging (always bf16 source, gload_lds)
  auto stageB = [&](int buf, int k0) {
    char* base = smem + buf * 16384 + 8192;
    #pragma unroll
    for (int i = 0; i < 2; i++) {
      const size_t go = (size_t)(wave * 32 + i * 16) * 512 + k0 + sgo;
      __builtin_amdgcn_global_load_lds(
          (const __attribute__((address_space(1))) void*)(Bb + go),
          (__attribute__((address_space(3))) void*)(base + wave * 2048 + i * 1024), 16, 0, 0);
    }
  };

  // fragment-read + MFMA for K-step t (shared by both staging paths)
  auto compute = [&](int t) {
    const u16* As = (const u16*)(smem + (t % 3) * 16384);
    const u16* Bs = As + 4096;   // +8192 B
    bf16x8 af[4], bfr[4];
    #pragma unroll
    for (int tt = 0; tt < 4; tt++) {
      const int ar = wr * 64 + tt * 16 + l15;
      const int br = wc * 64 + tt * 16 + l15;
      af[tt]  = *(const bf16x8*)&As[ar * 32 + foff];
      bfr[tt] = *(const bf16x8*)&Bs[br * 32 + foff];
    }
    #pragma unroll
    for (int mt = 0; mt < 4; mt++)
      #pragma unroll
      for (int nt = 0; nt < 4; nt++)
        acc[mt][nt] = __builtin_amdgcn_mfma_f32_16x16x32_bf16(af[mt], bfr[nt], acc[mt][nt], 0, 0, 0);
  };

  if constexpr (AFP32) {
    // ---- A staged from fp32 with inline convert (3 named reg sets) ----
    const float* Ap = Af32 + (size_t)by * 128 * 512
                    + (size_t)(wave * 32 + srl) * 512 + sc * 8;
    float4 rs[3][4];
    auto issueStage = [&](int st) {     // st compile-time under full unroll
      const int buf = st % 3, k0 = st * 32;
      stageB(buf, k0);                  // 2 vmem (B first)
      const float* p = Ap + k0;
      rs[st % 3][0] = *(const float4*)p;            // 4 vmem (A fp32)
      rs[st % 3][1] = *(const float4*)(p + 4);
      rs[st % 3][2] = *(const float4*)(p + 8192);   // +16 rows
      rs[st % 3][3] = *(const float4*)(p + 8196);
    };
    auto writeA = [&](int t) {
      const int s = t % 3;
      uint4* dst = (uint4*)(smem + (t % 3) * 16384 + wave * 2048 + lane * 16);
      uint4 w;
      w.x = pk2(rs[s][0].x, rs[s][0].y); w.y = pk2(rs[s][0].z, rs[s][0].w);
      w.z = pk2(rs[s][1].x, rs[s][1].y); w.w = pk2(rs[s][1].z, rs[s][1].w);
      dst[0]  = w;                       // i=0 chunk (1024 B across wave)
      w.x = pk2(rs[s][2].x, rs[s][2].y); w.y = pk2(rs[s][2].z, rs[s][2].w);
      w.z = pk2(rs[s][3].x, rs[s][3].y); w.w = pk2(rs[s][3].z, rs[s][3].w);
      dst[64] = w;                       // i=1 chunk (+1024 B)
    };

    issueStage(0);
    issueStage(1);
    #pragma unroll
    for (int t = 0; t < 16; t++) {
      if (t + 2 < 16) issueStage(t + 2);           // rs[(t+2)%3] free (consumed at t-1)
      // stage t's 6 vmem done; t+1/t+2 (12) stay in flight
      if (t <= 13)      asm volatile("s_waitcnt vmcnt(12)" ::: "memory");
      else if (t == 14) asm volatile("s_waitcnt vmcnt(6)" ::: "memory");
      else              asm volatile("s_waitcnt vmcnt(0)" ::: "memory");
      writeA(t);                                   // just-in-time A into buf t%3
      asm volatile("s_waitcnt lgkmcnt(0)\n\ts_barrier" ::: "memory");  // publish A+B
      compute(t);
      asm volatile("s_waitcnt lgkmcnt(0)\n\ts_barrier" ::: "memory");  // fence buf reuse
    }
  } else {
    // ---- original: A+B both via gload_lds (bf16 source) ----
    auto stage32 = [&](int buf, int k0) {
      char* base = smem + buf * 16384;
      #pragma unroll
      for (int i = 0; i < 2; i++) {
        const size_t go = (size_t)(wave * 32 + i * 16) * 512 + k0 + sgo;
        __builtin_amdgcn_global_load_lds(
            (const __attribute__((address_space(1))) void*)(Ab + go),
            (__attribute__((address_space(3))) void*)(base + wave * 2048 + i * 1024), 16, 0, 0);
        __builtin_amdgcn_global_load_lds(
            (const __attribute__((address_space(1))) void*)(Bb + go),
            (__attribute__((address_space(3))) void*)(base + 8192 + wave * 2048 + i * 1024), 16, 0, 0);
      }
    };
    stage32(0, 0);
    stage32(1, 32);
    #pragma unroll
    for (int t = 0; t < 16; t++) {
      if (t + 2 < 16) stage32((t + 2) % 3, (t + 2) * 32);
      if (t <= 13)      asm volatile("s_waitcnt vmcnt(8)\n\ts_barrier" ::: "memory");
      else if (t == 14) asm volatile("s_waitcnt vmcnt(4)\n\ts_barrier" ::: "memory");
      else              asm volatile("s_waitcnt vmcnt(0)\n\ts_barrier" ::: "memory");
      compute(t);
      asm volatile("s_waitcnt lgkmcnt(0)\n\ts_barrier" ::: "memory");
    }
  }

  if (!EPI) {
    // LDS transpose (stride 144 u16) -> coalesced bf16x8 stores
    #pragma unroll
    for (int mt = 0; mt < 4; mt++)
      #pragma unroll
      for (int nt = 0; nt < 4; nt++)
        #pragma unroll
        for (int r = 0; r < 4; r++) {
          int row = wr * 64 + mt * 16 + lq * 4 + r;   // C/D: row=(lane>>4)*4+reg
          int col = wc * 64 + nt * 16 + l15;          //      col=lane&15
          Ct[row * 144 + col] = f2b(scaleC * acc[mt][nt][r]);
        }
    __syncthreads();
    u16* Cb = C + (size_t)by * 128 * 512 + bx * 128;
    #pragma unroll
    for (int i = 0; i < 8; i++) {
      int c = tid + i * 256;          // 2048 chunks of 8 bf16
      int row = c >> 4, cc = c & 15;
      *(bf16x8*)&Cb[(size_t)row * 512 + cc * 8] = *(const bf16x8*)&Ct[row * 144 + cc * 8];
    }
  } else {
    const int gi0 = bz * 1024 + by * 128;
    const int gj0 = bz * 1024 + bx * 128;
    float* rowsumP = statsP + 0      + bx * SLICE;   // private slices: no atomics
    float* colsumP = statsP + 262144 + by * SLICE;
    float* rowminP = statsP + 524288 + bx * SLICE;
    float* colminP = statsP + 786432 + by * SLICE;

    float csum[4] = {0.f, 0.f, 0.f, 0.f};
    float cmin[4] = {3e38f, 3e38f, 3e38f, 3e38f};
    #pragma unroll
    for (int mt = 0; mt < 4; mt++) {
      #pragma unroll
      for (int r = 0; r < 4; r++) {
        const int row = wr * 64 + mt * 16 + lq * 4 + r;
        float rsm = 0.f, rmn = 3e38f;
        #pragma unroll
        for (int nt = 0; nt < 4; nt++) {
          float y = acc[mt][nt][r];                        // -log2e*X + pen
          float u = __builtin_amdgcn_exp2f(y);             // e^{-X} (inf if masked)
          float s = __builtin_amdgcn_rcpf(1.f + u);        // sigmoid(X) (0 if masked)
          float e = __builtin_amdgcn_exp2f(LOG2E * s);     // exp(I)    (1 if masked)
          rsm += e;
          csum[nt] += e;
          rmn = fminf(rmn, y);
          cmin[nt] = fminf(cmin[nt], y);
        }
        redS[row * 33 + l15 + 16 * wc] = rsm;
        redM[row * 33 + l15 + 16 * wc] = rmn;
      }
    }
    // col reduce across quads, then park per-wr in LDS
    #pragma unroll
    for (int nt = 0; nt < 4; nt++) {
      float cs = csum[nt], cm = cmin[nt];
      cs += __shfl_xor(cs, 16); cm = fminf(cm, __shfl_xor(cm, 16));
      cs += __shfl_xor(cs, 32); cm = fminf(cm, __shfl_xor(cm, 32));
      if (lane < 16) {
        int j = wc * 64 + nt * 16 + l15;
        colS[j * 2 + wr] = cs;     // both wr halves parked separately (R8 race fix)
        colM[j * 2 + wr] = cm;
      }
    }
    __syncthreads();
    // final reduce + private-slice stores
    if (tid < 128) {
      float s = 0.f;
      #pragma unroll
      for (int j = 0; j < 32; j++) s += redS[tid * 33 + j];
      rowsumP[gi0 + tid] = s;
      colsumP[gj0 + tid] = colS[tid * 2] + colS[tid * 2 + 1];
    } else {
      const int r = tid - 128;
      float m = 3e38f;
      #pragma unroll
      for (int j = 0; j < 32; j++) m = fminf(m, redM[r * 33 + j]);
      rowminP[gi0 + r] = m;
      colminP[gj0 + r] = fminf(colM[r * 2], colM[r * 2 + 1]);
    }
  }
}

// ---------------- partial: out[b,h] += sum_{i in seg} src[i][h] * att[i] (atomicAdd) --------
// att[i] = exp(I_max)/sum over the 8 private stats slices; I_max = rcp(1+exp2(y_min)).
// uint4 loads (16 B/lane): wave rw handles rows i*4+rw; unroll 8 -> 128 B in flight/thread.
// Cross-wave combine via LDS, then 2 atomicAdds/thread. grid (8, 64).
__global__ __launch_bounds__(256) void partial_kernel(
    const u16* __restrict__ qb, const u16* __restrict__ ab,
    const void* __restrict__ q0, const void* __restrict__ a0,
    const void* __restrict__ qmask,
    const float* __restrict__ statsP, float* __restrict__ out)
{
  __shared__ float att[128];
  __shared__ float red[4][512];
  const int tid = threadIdx.x;
  const int seg = blockIdx.x;
  const int b = blockIdx.y >> 1, half = blockIdx.y & 1;
  if (tid < 128) {
    const int g = b * 1024 + seg * 128 + tid;
    const float* sumP = statsP + half * 262144;
    const float* minP = statsP + 524288 + half * 262144;
    float s = 0.f, m = 3e38f;
    #pragma unroll
    for (int s8 = 0; s8 < 8; s8++) {
      s += sumP[s8 * SLICE + g];
      m = fminf(m, minP[s8 * SLICE + g]);
    }
    float Imax = __builtin_amdgcn_rcpf(1.f + __builtin_amdgcn_exp2f(m));
    att[tid] = __expf(Imax) * __builtin_amdgcn_rcpf(s);
  }
  __syncthreads();
  const bool bf = inputs_are_bf16(qmask);
  const u16* base = bf ? (const u16*)(half ? a0 : q0) : (half ? ab : qb);
  const uint4* src = (const uint4*)(base + (size_t)b * 524288
                                    + (size_t)seg * 128 * 512);
  const int rw = tid >> 6;      // wave index = row group (0..3)
  const int lane = tid & 63;    // h-chunk: 8 bf16 at h0 = lane*8
  float a0v = 0.f, a1v = 0.f, a2v = 0.f, a3v = 0.f;
  float a4v = 0.f, a5v = 0.f, a6v = 0.f, a7v = 0.f;
  #pragma unroll 8
  for (int i = 0; i < 32; i++) {
    const int row = i * 4 + rw;
    uint4 w = src[(size_t)row * 64 + lane];   // 64 uint4 per 512-bf16 row
    float wt = att[row];
    a0v = fmaf(__uint_as_float(w.x << 16), wt, a0v);
    a1v = fmaf(__uint_as_float(w.x & 0xFFFF0000u), wt, a1v);
    a2v = fmaf(__uint_as_float(w.y << 16), wt, a2v);
    a3v = fmaf(__uint_as_float(w.y & 0xFFFF0000u), wt, a3v);
    a4v = fmaf(__uint_as_float(w.z << 16), wt, a4v);
    a5v = fmaf(__uint_as_float(w.z & 0xFFFF0000u), wt, a5v);
    a6v = fmaf(__uint_as_float(w.w << 16), wt, a6v);
    a7v = fmaf(__uint_as_float(w.w & 0xFFFF0000u), wt, a7v);
  }
  *(float4*)&red[rw][lane * 8]     = make_float4(a0v, a1v, a2v, a3v);
  *(float4*)&red[rw][lane * 8 + 4] = make_float4(a4v, a5v, a6v, a7v);
  __syncthreads();
  const int h = tid * 2;
  float s0 = red[0][h]     + red[1][h]     + red[2][h]     + red[3][h];
  float s1 = red[0][h + 1] + red[1][h + 1] + red[2][h + 1] + red[3][h + 1];
  float* ob = out + half * 16384 + b * 512 + h;
  atomicAdd(&ob[0], s0);
  atomicAdd(&ob[1], s1);
}

extern "C" void kernel_launch(void* const* d_in, const int* in_sizes, int n_in,
                              void* d_out, int out_size, void* d_ws, size_t ws_size,
                              hipStream_t stream) {
  const void* q  = d_in[0];
  const void* a  = d_in[1];
  const void* U  = d_in[2];
  const void* qm = d_in[3];
  const void* am = d_in[4];
  float* out = (float*)d_out;

  char* ws = (char*)d_ws;
  u16* qb    = (u16*)ws;                       //  33,554,432 B
  u16* ab    = (u16*)(ws + 33554432);          //  33,554,432 B
  u16* qU    = (u16*)(ws + 67108864);          //  33,554,432 B (holds -log2e * qU)
  u16* Ut    = (u16*)(ws + 100663296);         //     524,288 B (dead after gemm<0>)
  float* statsP = (float*)(ws + 100663296);    //   4,194,304 B (overlays Ut; written by gemm<1>)
                                               //   total 104,857,600 B = 100 MiB

  const bool host_bf = (in_sizes[0] == 33554432);   // exact bf16 byte count for q
  prep_all<<<dim3(64), dim3(256), 0, stream>>>(q, a, U, qm, qb, ab, Ut, out);
  if (host_bf) {
    // bf16 contingency: original gload_lds staging reading q directly via alias
    gemm_bt<0, 0><<<dim3(4, 256, 1), dim3(256), 0, stream>>>(
        qb, Ut, qU, NLOG2E, (size_t)0, (size_t)0, qm, am, statsP,
        (const u16*)q, (const u16*)nullptr,
        nullptr, nullptr, nullptr, nullptr, nullptr);
  } else {
    // fp32 main path: inline fp32 A-staging + 8192 fused convert blocks (q->qb, a->ab)
    gemm_bt<0, 1><<<dim3(4, 2304, 1), dim3(256), 0, stream>>>(
        qb, Ut, qU, NLOG2E, (size_t)0, (size_t)0, qm, am, statsP,
        (const u16*)nullptr, (const u16*)nullptr,
        q, qb, a, ab, (const float*)q);
  }
  // per batch: y = qU[b] @ ab[b]^T = -log2e * X (+pen), fused epilogue, private-slice stats
  gemm_bt<1, 0><<<dim3(8, 8, 32), dim3(256), 0, stream>>>(
      qU, ab, (u16*)nullptr, 1.f, (size_t)524288, (size_t)524288, qm, am, statsP,
      (const u16*)nullptr, (const u16*)a,
      nullptr, nullptr, nullptr, nullptr, nullptr);
  partial_kernel<<<dim3(8, 64), dim3(256), 0, stream>>>(qb, ab, q, a, qm, statsP, out);
}

// Round 7
// 257.065 us; speedup vs baseline: 1.0595x; 1.0595x over previous
//
#include <hip/hip_runtime.h>

typedef __attribute__((ext_vector_type(8))) short bf16x8;   // 8 bf16 (4 VGPRs)
typedef __attribute__((ext_vector_type(4))) float f32x4;    // MFMA C/D
typedef unsigned short u16;
typedef unsigned int u32;

#define NLOG2E -1.44269504088896f   // -log2(e)
#define LOG2E   1.44269504088896f
#define SLICE 32768                 // one stats slice (32768 rows/cols total)

__device__ __forceinline__ float bf2f(u16 x) {
  union { u32 u; float f; } v; v.u = ((u32)x) << 16; return v.f;
}
__device__ __forceinline__ u16 f2b(float f) {
  union { float f; u32 u; } v; v.f = f;
  return (u16)((v.u + 0x7FFFu + ((v.u >> 16) & 1u)) >> 16);
}
// pack two fp32 -> one u32 of two bf16 (RNE), pure register ops (no alloca)
__device__ __forceinline__ u32 pk2(float lo, float hi) {
  return (u32)f2b(lo) | ((u32)f2b(hi) << 16);
}
// q_mask all ones: fp32 word0 = 0x3F800000, packed-bf16 word0 = 0x3F803F80
__device__ __forceinline__ bool inputs_are_bf16(const void* qmask) {
  return *(const u32*)qmask == 0x3F803F80u;
}

// fp32->bf16 convert, round-2 proven form (52-56us for 200MB): 4 consecutive
// float4 per thread, batched loads (MLP=4, VGPR=20). Lane-stride 64B is an L1
// illusion: a wave's 4 instructions fully consume the same cache lines -> no
// HBM-level over-fetch. R3/R4 lesson: grid-stride loops and wider batches get
// re-serialized by the compiler and run SLOWER.
__device__ __forceinline__ void convert16(const void* __restrict__ src,
                                          u16* __restrict__ dst, int idx) {
  const float4* s = (const float4*)src + (size_t)idx * 4;
  float4 v0 = s[0], v1 = s[1], v2 = s[2], v3 = s[3];
  uint4* d = (uint4*)dst + (size_t)idx * 2;
  uint4 w0, w1;
  w0.x = pk2(v0.x, v0.y); w0.y = pk2(v0.z, v0.w);
  w0.z = pk2(v1.x, v1.y); w0.w = pk2(v1.z, v1.w);
  w1.x = pk2(v2.x, v2.y); w1.y = pk2(v2.z, v2.w);
  w1.z = pk2(v3.x, v3.y); w1.w = pk2(v3.z, v3.w);
  d[0] = w0;
  d[1] = w1;
}

// ---------------- prep: U transpose + out zero ONLY (64 blocks, ~4 us).
__global__ __launch_bounds__(256) void prep_all(
    const void* __restrict__ q, const void* __restrict__ a,
    const void* __restrict__ U, const void* __restrict__ qmask,
    u16* __restrict__ qb, u16* __restrict__ ab, u16* __restrict__ Ut,
    float* __restrict__ out)
{
  const bool bf = inputs_are_bf16(qmask);
  const int t = threadIdx.x;
  const int bb = blockIdx.x;                      // [0,64)
  out[bb * 512 + t] = 0.f;                        // zero d_out (partial atomicAdds)
  out[bb * 512 + 256 + t] = 0.f;
  __shared__ u16 tile[64][65];
  const int bx = bb & 7, by = bb >> 3;
  #pragma unroll
  for (int i = 0; i < 16; i++) {
    int r = i * 4 + (t >> 6);
    int c = t & 63;
    size_t gi = (size_t)(by * 64 + r) * 512 + bx * 64 + c;
    tile[c][r] = bf ? ((const u16*)U)[gi] : f2b(((const float*)U)[gi]);
  }
  __syncthreads();
  #pragma unroll
  for (int i = 0; i < 16; i++) {
    int r = i * 4 + (t >> 6);
    int c = t & 63;
    Ut[(size_t)(bx * 64 + r) * 512 + by * 64 + c] = tile[r][c];
  }
}

// ---------------- 128x128 bf16 MFMA GEMM, C = A * B^T ----------------------------------
// Ring of 3 LDS buffers (48 KB + 1 KB masks -> 3 blocks/CU). B staged via
// global_load_lds width=16. 2-bit XOR swizzle slot = lq ^ ((row>>1)&3).
// AFP32==1 (gemm<0> fp32 main path): A staged from fp32 q with INLINE convert:
//   per stage/wave: 2 B-gload_lds + 4 coalesced float4 loads (6 vmem) into one of
//   3 named register sets (full unroll -> compile-time indices); steady gate
//   "s_waitcnt vmcnt(12)" = 2 stages in flight; then pk2 + 2x ds_write_b128,
//   lgkmcnt(0)+barrier publishes A+B, MFMA, end barrier fences buffer reuse.
//   R7: bx==0 blocks ALSO write their staged bf16 tile to qb (registers already
//   hold it -> qb produced with ZERO extra reads; R6's duplicate 67MB q read was
//   the regression). The 2 stores/iter are oldest-in-queue at every vmcnt gate ->
//   drain harmlessly. Extra grid blocks (y>=256): 4096 a->ab convert blocks.
// AFP32==0: original gload_lds A-staging (bf16 ws or alias), gates vmcnt 8/4/0.
// EPI==1 only: XCD remap (2-col x 4-row region per XCD) + mask-penalty acc init +
//   fused sigmoid/exp epilogue with private-slice stats (no atomics).
template<int EPI, int AFP32>
__global__ __launch_bounds__(256, 3) void gemm_bt(
    const u16* __restrict__ A, const u16* __restrict__ B,
    u16* __restrict__ C, float scaleC,
    size_t strideA, size_t strideB,
    const void* __restrict__ q_mask, const void* __restrict__ a_mask,
    float* __restrict__ statsP,
    const u16* __restrict__ A_alias, const u16* __restrict__ B_alias,
    u16* __restrict__ wbA_dst,
    const void* __restrict__ convA_src, u16* __restrict__ convA_dst,
    const float* __restrict__ Af32)
{
  if constexpr (EPI == 0 && AFP32 == 1) {
    if (blockIdx.y >= 256) {
      // fused a->ab convert blocks (overlap the GEMM on the CU array)
      const int cid = (blockIdx.y - 256) * 4 + blockIdx.x;   // [0, 4096)
      convert16(convA_src, convA_dst, cid * 256 + (int)threadIdx.x);
      return;
    }
  }

  __shared__ __align__(16) char smem[50176];
  // ring buf i at smem + i*16384: A 8 KB (128 rows x 32 K, 64 B/row) then B 8 KB
  u16* Ct  = (u16*)smem;                 // 128x144 u16 = 36864 B (EPI=0 epilogue, reuse)
  float* redS = (float*)smem;            // 128x33 f32 = 16896 B (EPI=1 epilogue, reuse)
  float* redM = (float*)(smem + 16896);  // 128x33 f32 (post-loop only)
  float* colS = (float*)(smem + 33792);  // 128x2 f32: col sums per wr half
  float* colM = (float*)(smem + 34816);  // 128x2 f32: col mins per wr half
  float* qp = (float*)(smem + 49152);    // 128 f32 penalties
  float* ap = (float*)(smem + 49664);    // 128 f32

  int bx = blockIdx.x, by = blockIdx.y;
  const int bz = blockIdx.z;
  if (EPI) {
    // XCD clustering: k = blockIdx.x is the XCD (flat%8); slot s = blockIdx.y.
    const int k = blockIdx.x, s = blockIdx.y;
    bx = (k & 3) * 2 + (s & 1);
    by = (k >> 2) * 4 + (s >> 1);
  }
  const int tid  = threadIdx.x;
  const int lane = tid & 63;
  const int wave = tid >> 6;
  const int wr = wave >> 1, wc = wave & 1;   // 2x2 wave grid, 64x64 each
  const int l15 = lane & 15, lq = lane >> 4; // lane-in-16, quad

  const bool bfin = inputs_are_bf16(q_mask);
  const u16* Asel = (bfin && A_alias) ? A_alias : A;
  const u16* Bsel = (bfin && B_alias) ? B_alias : B;

  // staging lane map: row_local = lane>>2, phys slot = lane&3,
  // logical chunk = slot ^ ((row>>1)&3) -> (lane&3) ^ ((lane>>3)&3)
  const int srl  = lane >> 2;
  const int sc   = (lane & 3) ^ ((lane >> 3) & 3);
  const size_t sgo = (size_t)srl * 512 + sc * 8;   // per-lane elem offset within a stage
  // fragment read: phys slot = lq ^ ((arow>>1)&3) -> lane-constant
  const int foff = ((lq ^ ((l15 >> 1) & 3)) * 8);

  const u16* Ab = Asel + strideA * bz + (size_t)by * 128 * 512;
  const u16* Bb = Bsel + strideB * bz + (size_t)bx * 128 * 512;

  if (EPI) {
    if (tid < 128) {
      int gi = bz * 1024 + by * 128 + tid;
      float v = bfin ? bf2f(((const u16*)q_mask)[gi]) : ((const float*)q_mask)[gi];
      qp[tid] = (v > 0.f) ? 0.f : 1e30f;
    } else {
      int gj = bz * 1024 + bx * 128 + (tid - 128);
      float v = bfin ? bf2f(((const u16*)a_mask)[gj]) : ((const float*)a_mask)[gj];
      ap[tid - 128] = (v > 0.f) ? 0.f : 1e30f;
    }
    __syncthreads();   // drains mask loads before any K-loop staging
  }

  f32x4 acc[4][4];
  if (EPI) {
    #pragma unroll
    for (int mt = 0; mt < 4; mt++)
      #pragma unroll
      for (int nt = 0; nt < 4; nt++) {
        float cp = ap[wc * 64 + nt * 16 + l15];
        #pragma unroll
        for (int r = 0; r < 4; r++)
          acc[mt][nt][r] = qp[wr * 64 + mt * 16 + lq * 4 + r] + cp;
      }
  } else {
    #pragma unroll
    for (int i = 0; i < 4; i++)
      #pragma unroll
      for (int j = 0; j < 4; j++) {
        f32x4 z = {0.f, 0.f, 0.f, 0.f};
        acc[i][j] = z;
      }
  }

  // B-half staging (always bf16 source, gload_lds)
  auto stageB = [&](int buf, int k0) {
    char* base = smem + buf * 16384 + 8192;
    #pragma unroll
    for (int i = 0; i < 2; i++) {
      const size_t go = (size_t)(wave * 32 + i * 16) * 512 + k0 + sgo;
      __builtin_amdgcn_global_load_lds(
          (const __attribute__((address_space(1))) void*)(Bb + go),
          (__attribute__((address_space(3))) void*)(base + wave * 2048 + i * 1024), 16, 0, 0);
    }
  };

  // fragment-read + MFMA for K-step t (shared by both staging paths)
  auto compute = [&](int t) {
    const u16* As = (const u16*)(smem + (t % 3) * 16384);
    const u16* Bs = As + 4096;   // +8192 B
    bf16x8 af[4], bfr[4];
    #pragma unroll
    for (int tt = 0; tt < 4; tt++) {
      const int ar = wr * 64 + tt * 16 + l15;
      const int br = wc * 64 + tt * 16 + l15;
      af[tt]  = *(const bf16x8*)&As[ar * 32 + foff];
      bfr[tt] = *(const bf16x8*)&Bs[br * 32 + foff];
    }
    #pragma unroll
    for (int mt = 0; mt < 4; mt++)
      #pragma unroll
      for (int nt = 0; nt < 4; nt++)
        acc[mt][nt] = __builtin_amdgcn_mfma_f32_16x16x32_bf16(af[mt], bfr[nt], acc[mt][nt], 0, 0, 0);
  };

  if constexpr (AFP32) {
    // ---- A staged from fp32 with inline convert (3 named reg sets) ----
    const float* Ap = Af32 + (size_t)by * 128 * 512
                    + (size_t)(wave * 32 + srl) * 512 + sc * 8;
    float4 rs[3][4];
    auto issueStage = [&](int st) {     // st compile-time under full unroll
      const int k0 = st * 32;
      stageB(st % 3, k0);               // 2 vmem (B first)
      const float* p = Ap + k0;
      rs[st % 3][0] = *(const float4*)p;            // 4 vmem (A fp32)
      rs[st % 3][1] = *(const float4*)(p + 4);
      rs[st % 3][2] = *(const float4*)(p + 8192);   // +16 rows
      rs[st % 3][3] = *(const float4*)(p + 8196);
    };
    auto writeA = [&](int t) {
      const int s = t % 3;
      uint4* dst = (uint4*)(smem + s * 16384 + wave * 2048 + lane * 16);
      uint4 w0, w1;
      w0.x = pk2(rs[s][0].x, rs[s][0].y); w0.y = pk2(rs[s][0].z, rs[s][0].w);
      w0.z = pk2(rs[s][1].x, rs[s][1].y); w0.w = pk2(rs[s][1].z, rs[s][1].w);
      w1.x = pk2(rs[s][2].x, rs[s][2].y); w1.y = pk2(rs[s][2].z, rs[s][2].w);
      w1.z = pk2(rs[s][3].x, rs[s][3].y); w1.w = pk2(rs[s][3].z, rs[s][3].w);
      dst[0]  = w0;                      // i=0 chunk (1024 B across wave)
      dst[64] = w1;                      // i=1 chunk (+1024 B)
      if (bx == 0) {
        // registers already hold the bf16 tile -> free qb production (no re-read).
        // per 4-lane group rows equal, sc permutes {0..3} -> contiguous 64B stores.
        u16* qrow = wbA_dst + (size_t)(by * 128 + wave * 32 + srl) * 512 + t * 32 + sc * 8;
        *(uint4*)qrow            = w0;
        *(uint4*)(qrow + 8192)   = w1;   // +16 rows (16*512 u16)
      }
    };

    issueStage(0);
    issueStage(1);
    #pragma unroll
    for (int t = 0; t < 16; t++) {
      if (t + 2 < 16) issueStage(t + 2);           // rs[(t+2)%3] free (consumed at t-1)
      // stage t's 6 vmem done; t+1/t+2 (12) stay in flight (qb stores are oldest,
      // drain first -> gates stay correct, slightly conservative for bx==0)
      if (t <= 13)      asm volatile("s_waitcnt vmcnt(12)" ::: "memory");
      else if (t == 14) asm volatile("s_waitcnt vmcnt(6)" ::: "memory");
      else              asm volatile("s_waitcnt vmcnt(0)" ::: "memory");
      writeA(t);                                   // just-in-time A into buf t%3
      asm volatile("s_waitcnt lgkmcnt(0)\n\ts_barrier" ::: "memory");  // publish A+B
      compute(t);
      asm volatile("s_waitcnt lgkmcnt(0)\n\ts_barrier" ::: "memory");  // fence buf reuse
    }
  } else {
    // ---- original: A+B both via gload_lds (bf16 source) ----
    auto stage32 = [&](int buf, int k0) {
      char* base = smem + buf * 16384;
      #pragma unroll
      for (int i = 0; i < 2; i++) {
        const size_t go = (size_t)(wave * 32 + i * 16) * 512 + k0 + sgo;
        __builtin_amdgcn_global_load_lds(
            (const __attribute__((address_space(1))) void*)(Ab + go),
            (__attribute__((address_space(3))) void*)(base + wave * 2048 + i * 1024), 16, 0, 0);
        __builtin_amdgcn_global_load_lds(
            (const __attribute__((address_space(1))) void*)(Bb + go),
            (__attribute__((address_space(3))) void*)(base + 8192 + wave * 2048 + i * 1024), 16, 0, 0);
      }
    };
    stage32(0, 0);
    stage32(1, 32);
    #pragma unroll
    for (int t = 0; t < 16; t++) {
      if (t + 2 < 16) stage32((t + 2) % 3, (t + 2) * 32);
      if (t <= 13)      asm volatile("s_waitcnt vmcnt(8)\n\ts_barrier" ::: "memory");
      else if (t == 14) asm volatile("s_waitcnt vmcnt(4)\n\ts_barrier" ::: "memory");
      else              asm volatile("s_waitcnt vmcnt(0)\n\ts_barrier" ::: "memory");
      compute(t);
      asm volatile("s_waitcnt lgkmcnt(0)\n\ts_barrier" ::: "memory");
    }
  }

  if (!EPI) {
    // LDS transpose (stride 144 u16) -> coalesced bf16x8 stores
    #pragma unroll
    for (int mt = 0; mt < 4; mt++)
      #pragma unroll
      for (int nt = 0; nt < 4; nt++)
        #pragma unroll
        for (int r = 0; r < 4; r++) {
          int row = wr * 64 + mt * 16 + lq * 4 + r;   // C/D: row=(lane>>4)*4+reg
          int col = wc * 64 + nt * 16 + l15;          //      col=lane&15
          Ct[row * 144 + col] = f2b(scaleC * acc[mt][nt][r]);
        }
    __syncthreads();
    u16* Cb = C + (size_t)by * 128 * 512 + bx * 128;
    #pragma unroll
    for (int i = 0; i < 8; i++) {
      int c = tid + i * 256;          // 2048 chunks of 8 bf16
      int row = c >> 4, cc = c & 15;
      *(bf16x8*)&Cb[(size_t)row * 512 + cc * 8] = *(const bf16x8*)&Ct[row * 144 + cc * 8];
    }
  } else {
    const int gi0 = bz * 1024 + by * 128;
    const int gj0 = bz * 1024 + bx * 128;
    float* rowsumP = statsP + 0      + bx * SLICE;   // private slices: no atomics
    float* colsumP = statsP + 262144 + by * SLICE;
    float* rowminP = statsP + 524288 + bx * SLICE;
    float* colminP = statsP + 786432 + by * SLICE;

    float csum[4] = {0.f, 0.f, 0.f, 0.f};
    float cmin[4] = {3e38f, 3e38f, 3e38f, 3e38f};
    #pragma unroll
    for (int mt = 0; mt < 4; mt++) {
      #pragma unroll
      for (int r = 0; r < 4; r++) {
        const int row = wr * 64 + mt * 16 + lq * 4 + r;
        float rsm = 0.f, rmn = 3e38f;
        #pragma unroll
        for (int nt = 0; nt < 4; nt++) {
          float y = acc[mt][nt][r];                        // -log2e*X + pen
          float u = __builtin_amdgcn_exp2f(y);             // e^{-X} (inf if masked)
          float s = __builtin_amdgcn_rcpf(1.f + u);        // sigmoid(X) (0 if masked)
          float e = __builtin_amdgcn_exp2f(LOG2E * s);     // exp(I)    (1 if masked)
          rsm += e;
          csum[nt] += e;
          rmn = fminf(rmn, y);
          cmin[nt] = fminf(cmin[nt], y);
        }
        redS[row * 33 + l15 + 16 * wc] = rsm;
        redM[row * 33 + l15 + 16 * wc] = rmn;
      }
    }
    // col reduce across quads, then park per-wr in LDS
    #pragma unroll
    for (int nt = 0; nt < 4; nt++) {
      float cs = csum[nt], cm = cmin[nt];
      cs += __shfl_xor(cs, 16); cm = fminf(cm, __shfl_xor(cm, 16));
      cs += __shfl_xor(cs, 32); cm = fminf(cm, __shfl_xor(cm, 32));
      if (lane < 16) {
        int j = wc * 64 + nt * 16 + l15;
        colS[j * 2 + wr] = cs;     // both wr halves parked separately (R8 race fix)
        colM[j * 2 + wr] = cm;
      }
    }
    __syncthreads();
    // final reduce + private-slice stores
    if (tid < 128) {
      float s = 0.f;
      #pragma unroll
      for (int j = 0; j < 32; j++) s += redS[tid * 33 + j];
      rowsumP[gi0 + tid] = s;
      colsumP[gj0 + tid] = colS[tid * 2] + colS[tid * 2 + 1];
    } else {
      const int r = tid - 128;
      float m = 3e38f;
      #pragma unroll
      for (int j = 0; j < 32; j++) m = fminf(m, redM[r * 33 + j]);
      rowminP[gi0 + r] = m;
      colminP[gj0 + r] = fminf(colM[r * 2], colM[r * 2 + 1]);
    }
  }
}

// ---------------- partial: out[b,h] += sum_{i in seg} src[i][h] * att[i] (atomicAdd) --------
// att[i] = exp(I_max)/sum over the 8 private stats slices; I_max = rcp(1+exp2(y_min)).
// uint4 loads (16 B/lane): wave rw handles rows i*4+rw; unroll 8 -> 128 B in flight/thread.
// Cross-wave combine via LDS, then 2 atomicAdds/thread. grid (8, 64).
__global__ __launch_bounds__(256) void partial_kernel(
    const u16* __restrict__ qb, const u16* __restrict__ ab,
    const void* __restrict__ q0, const void* __restrict__ a0,
    const void* __restrict__ qmask,
    const float* __restrict__ statsP, float* __restrict__ out)
{
  __shared__ float att[128];
  __shared__ float red[4][512];
  const int tid = threadIdx.x;
  const int seg = blockIdx.x;
  const int b = blockIdx.y >> 1, half = blockIdx.y & 1;
  if (tid < 128) {
    const int g = b * 1024 + seg * 128 + tid;
    const float* sumP = statsP + half * 262144;
    const float* minP = statsP + 524288 + half * 262144;
    float s = 0.f, m = 3e38f;
    #pragma unroll
    for (int s8 = 0; s8 < 8; s8++) {
      s += sumP[s8 * SLICE + g];
      m = fminf(m, minP[s8 * SLICE + g]);
    }
    float Imax = __builtin_amdgcn_rcpf(1.f + __builtin_amdgcn_exp2f(m));
    att[tid] = __expf(Imax) * __builtin_amdgcn_rcpf(s);
  }
  __syncthreads();
  const bool bf = inputs_are_bf16(qmask);
  const u16* base = bf ? (const u16*)(half ? a0 : q0) : (half ? ab : qb);
  const uint4* src = (const uint4*)(base + (size_t)b * 524288
                                    + (size_t)seg * 128 * 512);
  const int rw = tid >> 6;      // wave index = row group (0..3)
  const int lane = tid & 63;    // h-chunk: 8 bf16 at h0 = lane*8
  float a0v = 0.f, a1v = 0.f, a2v = 0.f, a3v = 0.f;
  float a4v = 0.f, a5v = 0.f, a6v = 0.f, a7v = 0.f;
  #pragma unroll 8
  for (int i = 0; i < 32; i++) {
    const int row = i * 4 + rw;
    uint4 w = src[(size_t)row * 64 + lane];   // 64 uint4 per 512-bf16 row
    float wt = att[row];
    a0v = fmaf(__uint_as_float(w.x << 16), wt, a0v);
    a1v = fmaf(__uint_as_float(w.x & 0xFFFF0000u), wt, a1v);
    a2v = fmaf(__uint_as_float(w.y << 16), wt, a2v);
    a3v = fmaf(__uint_as_float(w.y & 0xFFFF0000u), wt, a3v);
    a4v = fmaf(__uint_as_float(w.z << 16), wt, a4v);
    a5v = fmaf(__uint_as_float(w.z & 0xFFFF0000u), wt, a5v);
    a6v = fmaf(__uint_as_float(w.w << 16), wt, a6v);
    a7v = fmaf(__uint_as_float(w.w & 0xFFFF0000u), wt, a7v);
  }
  *(float4*)&red[rw][lane * 8]     = make_float4(a0v, a1v, a2v, a3v);
  *(float4*)&red[rw][lane * 8 + 4] = make_float4(a4v, a5v, a6v, a7v);
  __syncthreads();
  const int h = tid * 2;
  float s0 = red[0][h]     + red[1][h]     + red[2][h]     + red[3][h];
  float s1 = red[0][h + 1] + red[1][h + 1] + red[2][h + 1] + red[3][h + 1];
  float* ob = out + half * 16384 + b * 512 + h;
  atomicAdd(&ob[0], s0);
  atomicAdd(&ob[1], s1);
}

extern "C" void kernel_launch(void* const* d_in, const int* in_sizes, int n_in,
                              void* d_out, int out_size, void* d_ws, size_t ws_size,
                              hipStream_t stream) {
  const void* q  = d_in[0];
  const void* a  = d_in[1];
  const void* U  = d_in[2];
  const void* qm = d_in[3];
  const void* am = d_in[4];
  float* out = (float*)d_out;

  char* ws = (char*)d_ws;
  u16* qb    = (u16*)ws;                       //  33,554,432 B
  u16* ab    = (u16*)(ws + 33554432);          //  33,554,432 B
  u16* qU    = (u16*)(ws + 67108864);          //  33,554,432 B (holds -log2e * qU)
  u16* Ut    = (u16*)(ws + 100663296);         //     524,288 B (dead after gemm<0>)
  float* statsP = (float*)(ws + 100663296);    //   4,194,304 B (overlays Ut; written by gemm<1>)
                                               //   total 104,857,600 B = 100 MiB

  const bool host_bf = (in_sizes[0] == 33554432);   // exact bf16 byte count for q
  prep_all<<<dim3(64), dim3(256), 0, stream>>>(q, a, U, qm, qb, ab, Ut, out);
  if (host_bf) {
    // bf16 contingency: original gload_lds staging reading q directly via alias
    gemm_bt<0, 0><<<dim3(4, 256, 1), dim3(256), 0, stream>>>(
        qb, Ut, qU, NLOG2E, (size_t)0, (size_t)0, qm, am, statsP,
        (const u16*)q, (const u16*)nullptr,
        nullptr, nullptr, nullptr, nullptr);
  } else {
    // fp32 main path: inline fp32 A-staging (reads q ONCE); bx==0 blocks write
    // qb as a staging by-product; 4096 fused a->ab convert blocks overlap.
    gemm_bt<0, 1><<<dim3(4, 1280, 1), dim3(256), 0, stream>>>(
        qb, Ut, qU, NLOG2E, (size_t)0, (size_t)0, qm, am, statsP,
        (const u16*)nullptr, (const u16*)nullptr,
        qb, a, ab, (const float*)q);
  }
  // per batch: y = qU[b] @ ab[b]^T = -log2e * X (+pen), fused epilogue, private-slice stats
  gemm_bt<1, 0><<<dim3(8, 8, 32), dim3(256), 0, stream>>>(
      qU, ab, (u16*)nullptr, 1.f, (size_t)524288, (size_t)524288, qm, am, statsP,
      (const u16*)nullptr, (const u16*)a,
      nullptr, nullptr, nullptr, nullptr);
  partial_kernel<<<dim3(8, 64), dim3(256), 0, stream>>>(qb, ab, q, a, qm, statsP, out);
}

// Round 8
// 229.654 us; speedup vs baseline: 1.1860x; 1.1194x over previous
//
#include <hip/hip_runtime.h>

typedef __attribute__((ext_vector_type(8))) short bf16x8;   // 8 bf16 (4 VGPRs)
typedef __attribute__((ext_vector_type(4))) float f32x4;    // MFMA C/D
typedef unsigned short u16;
typedef unsigned int u32;

#define NLOG2E -1.44269504088896f   // -log2(e)
#define LOG2E   1.44269504088896f
#define SLICE 32768                 // one stats slice (32768 rows/cols total)

__device__ __forceinline__ float bf2f(u16 x) {
  union { u32 u; float f; } v; v.u = ((u32)x) << 16; return v.f;
}
__device__ __forceinline__ u16 f2b(float f) {
  union { float f; u32 u; } v; v.f = f;
  return (u16)((v.u + 0x7FFFu + ((v.u >> 16) & 1u)) >> 16);
}
// pack two fp32 -> one u32 of two bf16 (RNE), pure register ops (no alloca)
__device__ __forceinline__ u32 pk2(float lo, float hi) {
  return (u32)f2b(lo) | ((u32)f2b(hi) << 16);
}
// q_mask all ones: fp32 word0 = 0x3F800000, packed-bf16 word0 = 0x3F803F80
__device__ __forceinline__ bool inputs_are_bf16(const void* qmask) {
  return *(const u32*)qmask == 0x3F803F80u;
}

// fp32->bf16 convert, round-2 proven form (52-56us for 200MB; best of 3 measured
// variants): 4 consecutive float4 per thread, batched loads (MLP=4, VGPR=20).
// Lane-stride 64B is an L1 illusion: a wave's 4 instructions fully consume the
// same cache lines -> no HBM-level over-fetch. R3/R4 lesson: grid-stride loops
// and wider batches both get re-serialized by the compiler and run SLOWER.
__device__ __forceinline__ void convert16(const void* __restrict__ src,
                                          u16* __restrict__ dst, int idx) {
  const float4* s = (const float4*)src + (size_t)idx * 4;
  float4 v0 = s[0], v1 = s[1], v2 = s[2], v3 = s[3];
  uint4* d = (uint4*)dst + (size_t)idx * 2;
  uint4 w0, w1;
  w0.x = pk2(v0.x, v0.y); w0.y = pk2(v0.z, v0.w);
  w0.z = pk2(v1.x, v1.y); w0.w = pk2(v1.z, v1.w);
  w1.x = pk2(v2.x, v2.y); w1.y = pk2(v2.z, v2.w);
  w1.z = pk2(v3.x, v3.y); w1.w = pk2(v3.z, v3.w);
  d[0] = w0;
  d[1] = w1;
}

// ---------------- prep: U transpose + out zero (blocks 0..63); blocks 64..4159
// convert fp32 q -> qb (a is converted inside gemm_bt<0>'s extra blocks, where it
// overlaps the GEMM). When inputs are bf16 the convert blocks EXIT immediately.
__global__ __launch_bounds__(256) void prep_all(
    const void* __restrict__ q, const void* __restrict__ a,
    const void* __restrict__ U, const void* __restrict__ qmask,
    u16* __restrict__ qb, u16* __restrict__ ab, u16* __restrict__ Ut,
    float* __restrict__ out)
{
  const bool bf = inputs_are_bf16(qmask);
  const int t = threadIdx.x;
  if (blockIdx.x < 64) {
    const int bb = blockIdx.x;                      // [0,64)
    out[bb * 512 + t] = 0.f;                        // zero d_out (partial atomicAdds)
    out[bb * 512 + 256 + t] = 0.f;
    __shared__ u16 tile[64][65];
    const int bx = bb & 7, by = bb >> 3;
    #pragma unroll
    for (int i = 0; i < 16; i++) {
      int r = i * 4 + (t >> 6);
      int c = t & 63;
      size_t gi = (size_t)(by * 64 + r) * 512 + bx * 64 + c;
      tile[c][r] = bf ? ((const u16*)U)[gi] : f2b(((const float*)U)[gi]);
    }
    __syncthreads();
    #pragma unroll
    for (int i = 0; i < 16; i++) {
      int r = i * 4 + (t >> 6);
      int c = t & 63;
      Ut[(size_t)(bx * 64 + r) * 512 + by * 64 + c] = tile[r][c];
    }
  } else {
    if (bf) return;   // inputs already bf16: gemm/partial read q,a directly
    const int idx = (blockIdx.x - 64) * 256 + t;    // [0, 1048576)
    convert16(q, qb, idx);
  }
}

// ---------------- 128x128 bf16 MFMA GEMM, C = A * B^T (both [rows x 512] bf16 row-major) ----
// K-loop: 16 steps of BK=32 through a RING of 3 LDS buffers (3 x (A 8KB + B 8KB) = 48 KB),
// staged via global_load_lds width=16, prefetch depth 2 (8 loads in flight/wave).
// LDS total 50,176 B -> 3 blocks/CU. Steady-state gate: "s_waitcnt vmcnt(8); s_barrier"
// waits only the oldest in-flight stage's 4 loads. 2-bit XOR swizzle slot =
// lq ^ ((row>>1)&3) keeps b128 frag reads at 2-way bank aliasing (free).
// A_alias/B_alias: when inputs are bf16, read the original input buffer.
// EPI==0 FUSION: grid y >= 256 -> a->ab fp32->bf16 convert block (4096, overlap GEMM).
// R8 XCD PANEL CLUSTERING (replaces R2's 2x4 region remap):
//  - EPI==0 GEMM blocks: F = bx+4*by; XCD k=F&7 owns by in [32k,32k+32) -> each
//    A-panel (128KB) fetched by exactly ONE XCD L2 (32 panels = 4MB = one L2).
//    R6/R7 lesson: bx round-robins XCDs by default -> every A panel fetched 4x.
//  - EPI==1: XCD k (=blockIdx.x, flat%8==x) owns batches 4k..4k+3; slot s=y+8z ->
//    bz'=4k+s/64, tile=s%64. Each batch's qU+ab (2MB) lives in one L2; panels
//    fetched ONCE (old 2x4 remap: qU 4x, ab 2x).
// EPI==0: C = scaleC*(A B^T) bf16 via LDS-transpose -> coalesced bf16x8 stores.
// EPI==1: acc pre-init with mask penalties; fused sigmoid/exp epilogue with
//   private-slice stats (no atomics); wr column halves combined in LDS (R8 fix).
template<int EPI>
__global__ __launch_bounds__(256, 3) void gemm_bt(
    const u16* __restrict__ A, const u16* __restrict__ B,
    u16* __restrict__ C, float scaleC,
    size_t strideA, size_t strideB,
    const void* __restrict__ q_mask, const void* __restrict__ a_mask,
    float* __restrict__ statsP,
    const u16* __restrict__ A_alias, const u16* __restrict__ B_alias,
    const void* __restrict__ conv_src, u16* __restrict__ conv_dst)
{
  const bool bfin = inputs_are_bf16(q_mask);

  if (EPI == 0 && blockIdx.y >= 256) {
    // fused a->ab convert block (overlaps the GEMM blocks on the CU array)
    if (bfin) return;
    const int cid = (blockIdx.y - 256) * 4 + blockIdx.x;   // [0, 4096)
    const int idx = cid * 256 + (int)threadIdx.x;          // [0, 1048576)
    convert16(conv_src, conv_dst, idx);
    return;
  }

  __shared__ __align__(16) char smem[50176];
  // ring buf i at smem + i*16384: A 8 KB (128 rows x 32 K, 64 B/row) then B 8 KB
  u16* Ct  = (u16*)smem;                 // 128x144 u16 = 36864 B (EPI=0 epilogue, reuse)
  float* redS = (float*)smem;            // 128x33 f32 = 16896 B (EPI=1 epilogue, reuse)
  float* redM = (float*)(smem + 16896);  // 128x33 f32 (post-loop only)
  float* colS = (float*)(smem + 33792);  // 128x2 f32: col sums per wr half
  float* colM = (float*)(smem + 34816);  // 128x2 f32: col mins per wr half
  float* qp = (float*)(smem + 49152);    // 128 f32 penalties
  float* ap = (float*)(smem + 49664);    // 128 f32

  int bx = blockIdx.x, by = blockIdx.y;
  int bz = blockIdx.z;
  if (EPI) {
    // XCD z-clustering: bijective (k in [0,8)) x (s in [0,256)) -> (bz, tile).
    const int k = blockIdx.x;                       // = flat%8 = XCD
    const int s = blockIdx.y + 8 * (int)blockIdx.z; // [0,256) slot within XCD
    bz = k * 4 + (s >> 6);                          // 4 batches per XCD
    const int tt = s & 63;
    bx = tt & 7;
    by = tt >> 3;
  } else {
    // XCD by-clustering: F = bx+4*by in [0,1024); k=F&7 -> by' in [32k,32k+32).
    const int F = (int)blockIdx.x + 4 * (int)blockIdx.y;
    const int k = F & 7, j = F >> 3;                // j in [0,128)
    bx = j & 3;
    by = k * 32 + (j >> 2);
  }
  const int tid  = threadIdx.x;
  const int lane = tid & 63;
  const int wave = tid >> 6;
  const int wr = wave >> 1, wc = wave & 1;   // 2x2 wave grid, 64x64 each
  const int l15 = lane & 15, lq = lane >> 4; // lane-in-16, quad

  const u16* Asel = (bfin && A_alias) ? A_alias : A;
  const u16* Bsel = (bfin && B_alias) ? B_alias : B;

  // staging lane map (lane-invariant across wave/i): row_local = lane>>2, phys slot = lane&3,
  // logical chunk = slot ^ ((row>>1)&3) -> reduces to (lane&3) ^ ((lane>>3)&3)
  const int srl  = lane >> 2;
  const int sc   = (lane & 3) ^ ((lane >> 3) & 3);
  const size_t sgo = (size_t)srl * 512 + sc * 8;   // per-lane global offset within a stage
  // fragment read: phys slot = lq ^ ((arow>>1)&3) -> lane-constant (lq ^ ((l15>>1)&3))
  const int foff = ((lq ^ ((l15 >> 1) & 3)) * 8);

  const u16* Ab = Asel + strideA * bz + (size_t)by * 128 * 512;
  const u16* Bb = Bsel + strideB * bz + (size_t)bx * 128 * 512;

  if (EPI) {
    if (tid < 128) {
      int gi = bz * 1024 + by * 128 + tid;
      float v = bfin ? bf2f(((const u16*)q_mask)[gi]) : ((const float*)q_mask)[gi];
      qp[tid] = (v > 0.f) ? 0.f : 1e30f;
    } else {
      int gj = bz * 1024 + bx * 128 + (tid - 128);
      float v = bfin ? bf2f(((const u16*)a_mask)[gj]) : ((const float*)a_mask)[gj];
      ap[tid - 128] = (v > 0.f) ? 0.f : 1e30f;
    }
    __syncthreads();   // drains mask loads before any K-loop staging (vmcnt -> 0)
  }

  f32x4 acc[4][4];
  if (EPI) {
    #pragma unroll
    for (int mt = 0; mt < 4; mt++)
      #pragma unroll
      for (int nt = 0; nt < 4; nt++) {
        float cp = ap[wc * 64 + nt * 16 + l15];
        #pragma unroll
        for (int r = 0; r < 4; r++)
          acc[mt][nt][r] = qp[wr * 64 + mt * 16 + lq * 4 + r] + cp;
      }
  } else {
    #pragma unroll
    for (int i = 0; i < 4; i++)
      #pragma unroll
      for (int j = 0; j < 4; j++) {
        f32x4 z = {0.f, 0.f, 0.f, 0.f};
        acc[i][j] = z;
      }
  }

  // stage one BK=32 step (A 8KB + B 8KB) into ring buffer `buf`: 4 loads/wave
  auto stage32 = [&](int buf, int k0) {
    char* base = smem + buf * 16384;
    #pragma unroll
    for (int i = 0; i < 2; i++) {
      const size_t go = (size_t)(wave * 32 + i * 16) * 512 + k0 + sgo;
      __builtin_amdgcn_global_load_lds(
          (const __attribute__((address_space(1))) void*)(Ab + go),
          (__attribute__((address_space(3))) void*)(base + wave * 2048 + i * 1024), 16, 0, 0);
      __builtin_amdgcn_global_load_lds(
          (const __attribute__((address_space(1))) void*)(Bb + go),
          (__attribute__((address_space(3))) void*)(base + 8192 + wave * 2048 + i * 1024), 16, 0, 0);
    }
  };

  stage32(0, 0);
  stage32(1, 32);
  #pragma unroll
  for (int t = 0; t < 16; t++) {
    // stage into buf (t+2)%3 == (t-1)%3: all waves finished reading it at the
    // end-of-iteration (t-1) "lgkmcnt(0); s_barrier" gate
    if (t + 2 < 16) stage32((t + 2) % 3, (t + 2) * 32);
    // gate on the oldest in-flight stage only (4 loads); prefetches stay in flight
    if (t <= 13)      asm volatile("s_waitcnt vmcnt(8)\n\ts_barrier" ::: "memory");
    else if (t == 14) asm volatile("s_waitcnt vmcnt(4)\n\ts_barrier" ::: "memory");
    else              asm volatile("s_waitcnt vmcnt(0)\n\ts_barrier" ::: "memory");

    const u16* As = (const u16*)(smem + (t % 3) * 16384);
    const u16* Bs = (const u16*)(smem + (t % 3) * 16384 + 8192);
    bf16x8 af[4], bfr[4];
    #pragma unroll
    for (int tt = 0; tt < 4; tt++) {
      const int ar = wr * 64 + tt * 16 + l15;
      const int br = wc * 64 + tt * 16 + l15;
      af[tt]  = *(const bf16x8*)&As[ar * 32 + foff];
      bfr[tt] = *(const bf16x8*)&Bs[br * 32 + foff];
    }
    #pragma unroll
    for (int mt = 0; mt < 4; mt++)
      #pragma unroll
      for (int nt = 0; nt < 4; nt++)
        acc[mt][nt] = __builtin_amdgcn_mfma_f32_16x16x32_bf16(af[mt], bfr[nt], acc[mt][nt], 0, 0, 0);
    // all waves done reading this buffer before it is restaged / epilogue overlay
    asm volatile("s_waitcnt lgkmcnt(0)\n\ts_barrier" ::: "memory");
  }

  if (!EPI) {
    // LDS transpose (stride 144 u16) -> coalesced bf16x8 stores
    #pragma unroll
    for (int mt = 0; mt < 4; mt++)
      #pragma unroll
      for (int nt = 0; nt < 4; nt++)
        #pragma unroll
        for (int r = 0; r < 4; r++) {
          int row = wr * 64 + mt * 16 + lq * 4 + r;   // C/D: row=(lane>>4)*4+reg
          int col = wc * 64 + nt * 16 + l15;          //      col=lane&15
          Ct[row * 144 + col] = f2b(scaleC * acc[mt][nt][r]);
        }
    __syncthreads();
    u16* Cb = C + (size_t)by * 128 * 512 + bx * 128;
    #pragma unroll
    for (int i = 0; i < 8; i++) {
      int c = tid + i * 256;          // 2048 chunks of 8 bf16
      int row = c >> 4, cc = c & 15;
      *(bf16x8*)&Cb[(size_t)row * 512 + cc * 8] = *(const bf16x8*)&Ct[row * 144 + cc * 8];
    }
  } else {
    const int gi0 = bz * 1024 + by * 128;
    const int gj0 = bz * 1024 + bx * 128;
    float* rowsumP = statsP + 0      + bx * SLICE;   // private slices: no atomics
    float* colsumP = statsP + 262144 + by * SLICE;
    float* rowminP = statsP + 524288 + bx * SLICE;
    float* colminP = statsP + 786432 + by * SLICE;

    float csum[4] = {0.f, 0.f, 0.f, 0.f};
    float cmin[4] = {3e38f, 3e38f, 3e38f, 3e38f};
    #pragma unroll
    for (int mt = 0; mt < 4; mt++) {
      #pragma unroll
      for (int r = 0; r < 4; r++) {
        const int row = wr * 64 + mt * 16 + lq * 4 + r;
        float rsm = 0.f, rmn = 3e38f;
        #pragma unroll
        for (int nt = 0; nt < 4; nt++) {
          float y = acc[mt][nt][r];                        // -log2e*X + pen
          float u = __builtin_amdgcn_exp2f(y);             // e^{-X} (inf if masked)
          float s = __builtin_amdgcn_rcpf(1.f + u);        // sigmoid(X) (0 if masked)
          float e = __builtin_amdgcn_exp2f(LOG2E * s);     // exp(I)    (1 if masked)
          rsm += e;
          csum[nt] += e;
          rmn = fminf(rmn, y);
          cmin[nt] = fminf(cmin[nt], y);
        }
        redS[row * 33 + l15 + 16 * wc] = rsm;
        redM[row * 33 + l15 + 16 * wc] = rmn;
      }
    }
    // col reduce across quads (lanes l15 + 16*lq hold same col), then park per-wr in LDS
    #pragma unroll
    for (int nt = 0; nt < 4; nt++) {
      float cs = csum[nt], cm = cmin[nt];
      cs += __shfl_xor(cs, 16); cm = fminf(cm, __shfl_xor(cm, 16));
      cs += __shfl_xor(cs, 32); cm = fminf(cm, __shfl_xor(cm, 32));
      if (lane < 16) {
        int j = wc * 64 + nt * 16 + l15;
        colS[j * 2 + wr] = cs;     // both wr halves parked separately (R8 race fix)
        colM[j * 2 + wr] = cm;
      }
    }
    __syncthreads();
    // final reduce + private-slice stores
    if (tid < 128) {
      float s = 0.f;
      #pragma unroll
      for (int j = 0; j < 32; j++) s += redS[tid * 33 + j];
      rowsumP[gi0 + tid] = s;
      colsumP[gj0 + tid] = colS[tid * 2] + colS[tid * 2 + 1];
    } else {
      const int r = tid - 128;
      float m = 3e38f;
      #pragma unroll
      for (int j = 0; j < 32; j++) m = fminf(m, redM[r * 33 + j]);
      rowminP[gi0 + r] = m;
      colminP[gj0 + r] = fminf(colM[r * 2], colM[r * 2 + 1]);
    }
  }
}

// ---------------- partial: out[b,h] += sum_{i in seg} src[i][h] * att[i] (atomicAdd) --------
// att[i] = exp(I_max)/sum over the 8 private stats slices; I_max = rcp(1+exp2(y_min)).
// uint4 loads (16 B/lane): wave rw handles rows i*4+rw; unroll 8 -> 128 B in flight/thread.
// Cross-wave combine via LDS, then 2 atomicAdds/thread. grid (8, 64).
__global__ __launch_bounds__(256) void partial_kernel(
    const u16* __restrict__ qb, const u16* __restrict__ ab,
    const void* __restrict__ q0, const void* __restrict__ a0,
    const void* __restrict__ qmask,
    const float* __restrict__ statsP, float* __restrict__ out)
{
  __shared__ float att[128];
  __shared__ float red[4][512];
  const int tid = threadIdx.x;
  const int seg = blockIdx.x;
  const int b = blockIdx.y >> 1, half = blockIdx.y & 1;
  if (tid < 128) {
    const int g = b * 1024 + seg * 128 + tid;
    const float* sumP = statsP + half * 262144;
    const float* minP = statsP + 524288 + half * 262144;
    float s = 0.f, m = 3e38f;
    #pragma unroll
    for (int s8 = 0; s8 < 8; s8++) {
      s += sumP[s8 * SLICE + g];
      m = fminf(m, minP[s8 * SLICE + g]);
    }
    float Imax = __builtin_amdgcn_rcpf(1.f + __builtin_amdgcn_exp2f(m));
    att[tid] = __expf(Imax) * __builtin_amdgcn_rcpf(s);
  }
  __syncthreads();
  const bool bf = inputs_are_bf16(qmask);
  const u16* base = bf ? (const u16*)(half ? a0 : q0) : (half ? ab : qb);
  const uint4* src = (const uint4*)(base + (size_t)b * 524288
                                    + (size_t)seg * 128 * 512);
  const int rw = tid >> 6;      // wave index = row group (0..3)
  const int lane = tid & 63;    // h-chunk: 8 bf16 at h0 = lane*8
  float a0v = 0.f, a1v = 0.f, a2v = 0.f, a3v = 0.f;
  float a4v = 0.f, a5v = 0.f, a6v = 0.f, a7v = 0.f;
  #pragma unroll 8
  for (int i = 0; i < 32; i++) {
    const int row = i * 4 + rw;
    uint4 w = src[(size_t)row * 64 + lane];   // 64 uint4 per 512-bf16 row
    float wt = att[row];
    a0v = fmaf(__uint_as_float(w.x << 16), wt, a0v);
    a1v = fmaf(__uint_as_float(w.x & 0xFFFF0000u), wt, a1v);
    a2v = fmaf(__uint_as_float(w.y << 16), wt, a2v);
    a3v = fmaf(__uint_as_float(w.y & 0xFFFF0000u), wt, a3v);
    a4v = fmaf(__uint_as_float(w.z << 16), wt, a4v);
    a5v = fmaf(__uint_as_float(w.z & 0xFFFF0000u), wt, a5v);
    a6v = fmaf(__uint_as_float(w.w << 16), wt, a6v);
    a7v = fmaf(__uint_as_float(w.w & 0xFFFF0000u), wt, a7v);
  }
  *(float4*)&red[rw][lane * 8]     = make_float4(a0v, a1v, a2v, a3v);
  *(float4*)&red[rw][lane * 8 + 4] = make_float4(a4v, a5v, a6v, a7v);
  __syncthreads();
  const int h = tid * 2;
  float s0 = red[0][h]     + red[1][h]     + red[2][h]     + red[3][h];
  float s1 = red[0][h + 1] + red[1][h + 1] + red[2][h + 1] + red[3][h + 1];
  float* ob = out + half * 16384 + b * 512 + h;
  atomicAdd(&ob[0], s0);
  atomicAdd(&ob[1], s1);
}

extern "C" void kernel_launch(void* const* d_in, const int* in_sizes, int n_in,
                              void* d_out, int out_size, void* d_ws, size_t ws_size,
                              hipStream_t stream) {
  const void* q  = d_in[0];
  const void* a  = d_in[1];
  const void* U  = d_in[2];
  const void* qm = d_in[3];
  const void* am = d_in[4];
  float* out = (float*)d_out;

  char* ws = (char*)d_ws;
  u16* qb    = (u16*)ws;                       //  33,554,432 B
  u16* ab    = (u16*)(ws + 33554432);          //  33,554,432 B
  u16* qU    = (u16*)(ws + 67108864);          //  33,554,432 B (holds -log2e * qU)
  u16* Ut    = (u16*)(ws + 100663296);         //     524,288 B (dead after gemm<0>)
  float* statsP = (float*)(ws + 100663296);    //   4,194,304 B (overlays Ut; written by gemm<1>)
                                               //   total 104,857,600 B = 100 MiB

  // bf16 host fast path: only U-transpose/zero blocks; no convert blocks anywhere.
  const bool host_bf = (in_sizes[0] == 33554432);
  const int prep_blocks = host_bf ? 64 : 4160;       // 64 + 4096 q-convert
  const int g0_ny       = host_bf ? 256 : 1280;      // 256 GEMM rows + 1024 (=4096 blk) a-convert
  prep_all<<<dim3(prep_blocks), dim3(256), 0, stream>>>(q, a, U, qm, qb, ab, Ut, out);
  // qU[32768x512] = -log2e * ((q|qb) @ Ut^T); extra blocks convert a -> ab (overlapped)
  gemm_bt<0><<<dim3(4, g0_ny, 1), dim3(256), 0, stream>>>(
      qb, Ut, qU, NLOG2E, (size_t)0, (size_t)0, qm, am, statsP,
      (const u16*)q, (const u16*)nullptr, a, ab);
  // per batch: y = qU[b] @ (a|ab)[b]^T = -log2e * X (+pen), fused epilogue, private-slice stats
  gemm_bt<1><<<dim3(8, 8, 32), dim3(256), 0, stream>>>(
      qU, ab, (u16*)nullptr, 1.f, (size_t)524288, (size_t)524288, qm, am, statsP,
      (const u16*)nullptr, (const u16*)a, nullptr, nullptr);
  partial_kernel<<<dim3(8, 64), dim3(256), 0, stream>>>(qb, ab, q, a, qm, statsP, out);
}

// Round 9
// 228.908 us; speedup vs baseline: 1.1899x; 1.0033x over previous
//
#include <hip/hip_runtime.h>

typedef __attribute__((ext_vector_type(8))) short bf16x8;   // 8 bf16 (4 VGPRs)
typedef __attribute__((ext_vector_type(4))) float f32x4;    // MFMA C/D
typedef unsigned short u16;
typedef unsigned int u32;

#define NLOG2E -1.44269504088896f   // -log2(e)
#define LOG2E   1.44269504088896f
#define SLICE 32768                 // one stats slice (32768 rows/cols total)

__device__ __forceinline__ float bf2f(u16 x) {
  union { u32 u; float f; } v; v.u = ((u32)x) << 16; return v.f;
}
__device__ __forceinline__ u16 f2b(float f) {
  union { float f; u32 u; } v; v.f = f;
  return (u16)((v.u + 0x7FFFu + ((v.u >> 16) & 1u)) >> 16);
}
// pack two fp32 -> one u32 of two bf16 (RNE), pure register ops (no alloca)
__device__ __forceinline__ u32 pk2(float lo, float hi) {
  return (u32)f2b(lo) | ((u32)f2b(hi) << 16);
}
// q_mask all ones: fp32 word0 = 0x3F800000, packed-bf16 word0 = 0x3F803F80
__device__ __forceinline__ bool inputs_are_bf16(const void* qmask) {
  return *(const u32*)qmask == 0x3F803F80u;
}

// fp32->bf16 convert, round-2 proven form (best of 3 measured variants, ~3.7 TB/s):
// 4 consecutive float4 per thread, batched loads (MLP=4, VGPR=20). Lane-stride 64B
// is an L1 illusion: a wave's 4 instructions fully consume the same cache lines.
// R3/R4 lesson: grid-stride loops and wider batches get re-serialized -> SLOWER.
__device__ __forceinline__ void convert16(const void* __restrict__ src,
                                          u16* __restrict__ dst, int idx) {
  const float4* s = (const float4*)src + (size_t)idx * 4;
  float4 v0 = s[0], v1 = s[1], v2 = s[2], v3 = s[3];
  uint4* d = (uint4*)dst + (size_t)idx * 2;
  uint4 w0, w1;
  w0.x = pk2(v0.x, v0.y); w0.y = pk2(v0.z, v0.w);
  w0.z = pk2(v1.x, v1.y); w0.w = pk2(v1.z, v1.w);
  w1.x = pk2(v2.x, v2.y); w1.y = pk2(v2.z, v2.w);
  w1.z = pk2(v3.x, v3.y); w1.w = pk2(v3.z, v3.w);
  d[0] = w0;
  d[1] = w1;
}

// ---------------- prep: U transpose + out zero (blocks 0..63); blocks 64..4159
// convert fp32 q -> qb (a is converted inside gemm_bt<0>'s extra blocks, where it
// overlaps the GEMM). When inputs are bf16 the convert blocks EXIT immediately.
__global__ __launch_bounds__(256) void prep_all(
    const void* __restrict__ q, const void* __restrict__ a,
    const void* __restrict__ U, const void* __restrict__ qmask,
    u16* __restrict__ qb, u16* __restrict__ ab, u16* __restrict__ Ut,
    float* __restrict__ out)
{
  const bool bf = inputs_are_bf16(qmask);
  const int t = threadIdx.x;
  if (blockIdx.x < 64) {
    const int bb = blockIdx.x;                      // [0,64)
    out[bb * 512 + t] = 0.f;                        // zero d_out (partial atomicAdds)
    out[bb * 512 + 256 + t] = 0.f;
    __shared__ u16 tile[64][65];
    const int bx = bb & 7, by = bb >> 3;
    #pragma unroll
    for (int i = 0; i < 16; i++) {
      int r = i * 4 + (t >> 6);
      int c = t & 63;
      size_t gi = (size_t)(by * 64 + r) * 512 + bx * 64 + c;
      tile[c][r] = bf ? ((const u16*)U)[gi] : f2b(((const float*)U)[gi]);
    }
    __syncthreads();
    #pragma unroll
    for (int i = 0; i < 16; i++) {
      int r = i * 4 + (t >> 6);
      int c = t & 63;
      Ut[(size_t)(bx * 64 + r) * 512 + by * 64 + c] = tile[r][c];
    }
  } else {
    if (bf) return;   // inputs already bf16: gemm/partial read q,a directly
    const int idx = (blockIdx.x - 64) * 256 + t;    // [0, 1048576)
    convert16(q, qb, idx);
  }
}

// ---------------- 128x128 bf16 MFMA GEMM, C = A * B^T (both [rows x 512] bf16 row-major) ----
// R9: RING OF 2 LDS buffers (2 x (A 8KB + B 8KB) = 32 KB), LDS total 37,888 B ->
// 4 blocks/CU (was 3 with the 3-ring): +33% TLP attacks the latency-bound profile
// (R8: MfmaUtil 12%, VALUBusy 10%, Occ 26%, 2.4 TB/s — neither BW- nor compute-bound).
// Pipeline depth 1 (4 loads in flight/wave); per-wave stalls covered by wave-level
// overlap across 16 waves/CU (m97/m114 mechanism). Gate: "s_waitcnt vmcnt(4);
// s_barrier" — waits only stage t's 4 loads, t+1's stay in flight.
// Hazard: stage(t+1)->buf (t+1)&1 last read at t-1, fenced by that iteration's
// "lgkmcnt(0); s_barrier". 2-bit XOR swizzle slot = lq ^ ((row>>1)&3) keeps b128
// frag reads at 2-way bank aliasing (free).
// A_alias/B_alias: when inputs are bf16, read the original input buffer.
// EPI==0 FUSION: grid y >= 256 -> a->ab fp32->bf16 convert block (4096, overlap GEMM).
// R8 XCD PANEL CLUSTERING (kept):
//  - EPI==0 GEMM blocks: F = bx+4*by; XCD k=F&7 owns by in [32k,32k+32) -> each
//    A-panel fetched by exactly ONE XCD L2 (32 panels = 4MB = one L2).
//  - EPI==1: XCD k (=blockIdx.x, flat%8==x) owns batches 4k..4k+3; slot s=y+8z ->
//    bz'=4k+s/64, tile=s%64. Each batch's qU+ab (2MB) lives in one L2.
// EPI==0: C = scaleC*(A B^T) bf16 via LDS-transpose -> coalesced bf16x8 stores.
// EPI==1: acc pre-init with mask penalties; fused sigmoid/exp epilogue with
//   private-slice stats (no atomics); wr column halves combined in LDS.
// LDS map: ring buf i at i*16384 (0..32768). Epilogue overlays: Ct[128x144]=36864
// (EPI0); redS 0..16896, redM 16896..33792, colS 33792, colM 34816 (EPI1).
// masks qp/ap at 36864/37376 (outside ring; read only before K-loop). Total 37888.
template<int EPI>
__global__ __launch_bounds__(256, 4) void gemm_bt(
    const u16* __restrict__ A, const u16* __restrict__ B,
    u16* __restrict__ C, float scaleC,
    size_t strideA, size_t strideB,
    const void* __restrict__ q_mask, const void* __restrict__ a_mask,
    float* __restrict__ statsP,
    const u16* __restrict__ A_alias, const u16* __restrict__ B_alias,
    const void* __restrict__ conv_src, u16* __restrict__ conv_dst)
{
  const bool bfin = inputs_are_bf16(q_mask);

  if (EPI == 0 && blockIdx.y >= 256) {
    // fused a->ab convert block (overlaps the GEMM blocks on the CU array)
    if (bfin) return;
    const int cid = (blockIdx.y - 256) * 4 + blockIdx.x;   // [0, 4096)
    const int idx = cid * 256 + (int)threadIdx.x;          // [0, 1048576)
    convert16(conv_src, conv_dst, idx);
    return;
  }

  __shared__ __align__(16) char smem[37888];
  u16* Ct  = (u16*)smem;                 // 128x144 u16 = 36864 B (EPI=0 epilogue, reuse)
  float* redS = (float*)smem;            // 128x33 f32 = 16896 B (EPI=1 epilogue, reuse)
  float* redM = (float*)(smem + 16896);  // 128x33 f32 (post-loop only)
  float* colS = (float*)(smem + 33792);  // 128x2 f32: col sums per wr half
  float* colM = (float*)(smem + 34816);  // 128x2 f32: col mins per wr half
  float* qp = (float*)(smem + 36864);    // 128 f32 penalties (outside ring)
  float* ap = (float*)(smem + 37376);    // 128 f32

  int bx = blockIdx.x, by = blockIdx.y;
  int bz = blockIdx.z;
  if (EPI) {
    // XCD z-clustering: bijective (k in [0,8)) x (s in [0,256)) -> (bz, tile).
    const int k = blockIdx.x;                       // = flat%8 = XCD
    const int s = blockIdx.y + 8 * (int)blockIdx.z; // [0,256) slot within XCD
    bz = k * 4 + (s >> 6);                          // 4 batches per XCD
    const int tt = s & 63;
    bx = tt & 7;
    by = tt >> 3;
  } else {
    // XCD by-clustering: F = bx+4*by in [0,1024); k=F&7 -> by' in [32k,32k+32).
    const int F = (int)blockIdx.x + 4 * (int)blockIdx.y;
    const int k = F & 7, j = F >> 3;                // j in [0,128)
    bx = j & 3;
    by = k * 32 + (j >> 2);
  }
  const int tid  = threadIdx.x;
  const int lane = tid & 63;
  const int wave = tid >> 6;
  const int wr = wave >> 1, wc = wave & 1;   // 2x2 wave grid, 64x64 each
  const int l15 = lane & 15, lq = lane >> 4; // lane-in-16, quad

  const u16* Asel = (bfin && A_alias) ? A_alias : A;
  const u16* Bsel = (bfin && B_alias) ? B_alias : B;

  // staging lane map (lane-invariant across wave/i): row_local = lane>>2, phys slot = lane&3,
  // logical chunk = slot ^ ((row>>1)&3) -> reduces to (lane&3) ^ ((lane>>3)&3)
  const int srl  = lane >> 2;
  const int sc   = (lane & 3) ^ ((lane >> 3) & 3);
  const size_t sgo = (size_t)srl * 512 + sc * 8;   // per-lane global offset within a stage
  // fragment read: phys slot = lq ^ ((arow>>1)&3) -> lane-constant (lq ^ ((l15>>1)&3))
  const int foff = ((lq ^ ((l15 >> 1) & 3)) * 8);

  const u16* Ab = Asel + strideA * bz + (size_t)by * 128 * 512;
  const u16* Bb = Bsel + strideB * bz + (size_t)bx * 128 * 512;

  if (EPI) {
    if (tid < 128) {
      int gi = bz * 1024 + by * 128 + tid;
      float v = bfin ? bf2f(((const u16*)q_mask)[gi]) : ((const float*)q_mask)[gi];
      qp[tid] = (v > 0.f) ? 0.f : 1e30f;
    } else {
      int gj = bz * 1024 + bx * 128 + (tid - 128);
      float v = bfin ? bf2f(((const u16*)a_mask)[gj]) : ((const float*)a_mask)[gj];
      ap[tid - 128] = (v > 0.f) ? 0.f : 1e30f;
    }
    __syncthreads();   // drains mask loads before any K-loop staging (vmcnt -> 0)
  }

  f32x4 acc[4][4];
  if (EPI) {
    #pragma unroll
    for (int mt = 0; mt < 4; mt++)
      #pragma unroll
      for (int nt = 0; nt < 4; nt++) {
        float cp = ap[wc * 64 + nt * 16 + l15];
        #pragma unroll
        for (int r = 0; r < 4; r++)
          acc[mt][nt][r] = qp[wr * 64 + mt * 16 + lq * 4 + r] + cp;
      }
  } else {
    #pragma unroll
    for (int i = 0; i < 4; i++)
      #pragma unroll
      for (int j = 0; j < 4; j++) {
        f32x4 z = {0.f, 0.f, 0.f, 0.f};
        acc[i][j] = z;
      }
  }

  // stage one BK=32 step (A 8KB + B 8KB) into ring buffer `buf`: 4 loads/wave
  auto stage32 = [&](int buf, int k0) {
    char* base = smem + buf * 16384;
    #pragma unroll
    for (int i = 0; i < 2; i++) {
      const size_t go = (size_t)(wave * 32 + i * 16) * 512 + k0 + sgo;
      __builtin_amdgcn_global_load_lds(
          (const __attribute__((address_space(1))) void*)(Ab + go),
          (__attribute__((address_space(3))) void*)(base + wave * 2048 + i * 1024), 16, 0, 0);
      __builtin_amdgcn_global_load_lds(
          (const __attribute__((address_space(1))) void*)(Bb + go),
          (__attribute__((address_space(3))) void*)(base + 8192 + wave * 2048 + i * 1024), 16, 0, 0);
    }
  };

  stage32(0, 0);
  #pragma unroll
  for (int t = 0; t < 16; t++) {
    // stage into buf (t+1)&1: last read at iter t-1, fenced by its end barrier
    if (t + 1 < 16) stage32((t + 1) & 1, (t + 1) * 32);
    // gate on stage t's 4 loads only; t+1's prefetch stays in flight
    if (t < 15) asm volatile("s_waitcnt vmcnt(4)\n\ts_barrier" ::: "memory");
    else        asm volatile("s_waitcnt vmcnt(0)\n\ts_barrier" ::: "memory");

    const u16* As = (const u16*)(smem + (t & 1) * 16384);
    const u16* Bs = (const u16*)(smem + (t & 1) * 16384 + 8192);
    bf16x8 af[4], bfr[4];
    #pragma unroll
    for (int tt = 0; tt < 4; tt++) {
      const int ar = wr * 64 + tt * 16 + l15;
      const int br = wc * 64 + tt * 16 + l15;
      af[tt]  = *(const bf16x8*)&As[ar * 32 + foff];
      bfr[tt] = *(const bf16x8*)&Bs[br * 32 + foff];
    }
    #pragma unroll
    for (int mt = 0; mt < 4; mt++)
      #pragma unroll
      for (int nt = 0; nt < 4; nt++)
        acc[mt][nt] = __builtin_amdgcn_mfma_f32_16x16x32_bf16(af[mt], bfr[nt], acc[mt][nt], 0, 0, 0);
    // all waves done reading this buffer before it is restaged / epilogue overlay
    asm volatile("s_waitcnt lgkmcnt(0)\n\ts_barrier" ::: "memory");
  }

  if (!EPI) {
    // LDS transpose (stride 144 u16) -> coalesced bf16x8 stores
    #pragma unroll
    for (int mt = 0; mt < 4; mt++)
      #pragma unroll
      for (int nt = 0; nt < 4; nt++)
        #pragma unroll
        for (int r = 0; r < 4; r++) {
          int row = wr * 64 + mt * 16 + lq * 4 + r;   // C/D: row=(lane>>4)*4+reg
          int col = wc * 64 + nt * 16 + l15;          //      col=lane&15
          Ct[row * 144 + col] = f2b(scaleC * acc[mt][nt][r]);
        }
    __syncthreads();
    u16* Cb = C + (size_t)by * 128 * 512 + bx * 128;
    #pragma unroll
    for (int i = 0; i < 8; i++) {
      int c = tid + i * 256;          // 2048 chunks of 8 bf16
      int row = c >> 4, cc = c & 15;
      *(bf16x8*)&Cb[(size_t)row * 512 + cc * 8] = *(const bf16x8*)&Ct[row * 144 + cc * 8];
    }
  } else {
    const int gi0 = bz * 1024 + by * 128;
    const int gj0 = bz * 1024 + bx * 128;
    float* rowsumP = statsP + 0      + bx * SLICE;   // private slices: no atomics
    float* colsumP = statsP + 262144 + by * SLICE;
    float* rowminP = statsP + 524288 + bx * SLICE;
    float* colminP = statsP + 786432 + by * SLICE;

    float csum[4] = {0.f, 0.f, 0.f, 0.f};
    float cmin[4] = {3e38f, 3e38f, 3e38f, 3e38f};
    #pragma unroll
    for (int mt = 0; mt < 4; mt++) {
      #pragma unroll
      for (int r = 0; r < 4; r++) {
        const int row = wr * 64 + mt * 16 + lq * 4 + r;
        float rsm = 0.f, rmn = 3e38f;
        #pragma unroll
        for (int nt = 0; nt < 4; nt++) {
          float y = acc[mt][nt][r];                        // -log2e*X + pen
          float u = __builtin_amdgcn_exp2f(y);             // e^{-X} (inf if masked)
          float s = __builtin_amdgcn_rcpf(1.f + u);        // sigmoid(X) (0 if masked)
          float e = __builtin_amdgcn_exp2f(LOG2E * s);     // exp(I)    (1 if masked)
          rsm += e;
          csum[nt] += e;
          rmn = fminf(rmn, y);
          cmin[nt] = fminf(cmin[nt], y);
        }
        redS[row * 33 + l15 + 16 * wc] = rsm;
        redM[row * 33 + l15 + 16 * wc] = rmn;
      }
    }
    // col reduce across quads (lanes l15 + 16*lq hold same col), then park per-wr in LDS
    #pragma unroll
    for (int nt = 0; nt < 4; nt++) {
      float cs = csum[nt], cm = cmin[nt];
      cs += __shfl_xor(cs, 16); cm = fminf(cm, __shfl_xor(cm, 16));
      cs += __shfl_xor(cs, 32); cm = fminf(cm, __shfl_xor(cm, 32));
      if (lane < 16) {
        int j = wc * 64 + nt * 16 + l15;
        colS[j * 2 + wr] = cs;     // both wr halves parked separately (R8 race fix)
        colM[j * 2 + wr] = cm;
      }
    }
    __syncthreads();
    // final reduce + private-slice stores
    if (tid < 128) {
      float s = 0.f;
      #pragma unroll
      for (int j = 0; j < 32; j++) s += redS[tid * 33 + j];
      rowsumP[gi0 + tid] = s;
      colsumP[gj0 + tid] = colS[tid * 2] + colS[tid * 2 + 1];
    } else {
      const int r = tid - 128;
      float m = 3e38f;
      #pragma unroll
      for (int j = 0; j < 32; j++) m = fminf(m, redM[r * 33 + j]);
      rowminP[gi0 + r] = m;
      colminP[gj0 + r] = fminf(colM[r * 2], colM[r * 2 + 1]);
    }
  }
}

// ---------------- partial: out[b,h] += sum_{i in seg} src[i][h] * att[i] (atomicAdd) --------
// att[i] = exp(I_max)/sum over the 8 private stats slices; I_max = rcp(1+exp2(y_min)).
// uint4 loads (16 B/lane): wave rw handles rows i*4+rw; unroll 8 -> 128 B in flight/thread.
// Cross-wave combine via LDS, then 2 atomicAdds/thread. grid (8, 64).
__global__ __launch_bounds__(256) void partial_kernel(
    const u16* __restrict__ qb, const u16* __restrict__ ab,
    const void* __restrict__ q0, const void* __restrict__ a0,
    const void* __restrict__ qmask,
    const float* __restrict__ statsP, float* __restrict__ out)
{
  __shared__ float att[128];
  __shared__ float red[4][512];
  const int tid = threadIdx.x;
  const int seg = blockIdx.x;
  const int b = blockIdx.y >> 1, half = blockIdx.y & 1;
  if (tid < 128) {
    const int g = b * 1024 + seg * 128 + tid;
    const float* sumP = statsP + half * 262144;
    const float* minP = statsP + 524288 + half * 262144;
    float s = 0.f, m = 3e38f;
    #pragma unroll
    for (int s8 = 0; s8 < 8; s8++) {
      s += sumP[s8 * SLICE + g];
      m = fminf(m, minP[s8 * SLICE + g]);
    }
    float Imax = __builtin_amdgcn_rcpf(1.f + __builtin_amdgcn_exp2f(m));
    att[tid] = __expf(Imax) * __builtin_amdgcn_rcpf(s);
  }
  __syncthreads();
  const bool bf = inputs_are_bf16(qmask);
  const u16* base = bf ? (const u16*)(half ? a0 : q0) : (half ? ab : qb);
  const uint4* src = (const uint4*)(base + (size_t)b * 524288
                                    + (size_t)seg * 128 * 512);
  const int rw = tid >> 6;      // wave index = row group (0..3)
  const int lane = tid & 63;    // h-chunk: 8 bf16 at h0 = lane*8
  float a0v = 0.f, a1v = 0.f, a2v = 0.f, a3v = 0.f;
  float a4v = 0.f, a5v = 0.f, a6v = 0.f, a7v = 0.f;
  #pragma unroll 8
  for (int i = 0; i < 32; i++) {
    const int row = i * 4 + rw;
    uint4 w = src[(size_t)row * 64 + lane];   // 64 uint4 per 512-bf16 row
    float wt = att[row];
    a0v = fmaf(__uint_as_float(w.x << 16), wt, a0v);
    a1v = fmaf(__uint_as_float(w.x & 0xFFFF0000u), wt, a1v);
    a2v = fmaf(__uint_as_float(w.y << 16), wt, a2v);
    a3v = fmaf(__uint_as_float(w.y & 0xFFFF0000u), wt, a3v);
    a4v = fmaf(__uint_as_float(w.z << 16), wt, a4v);
    a5v = fmaf(__uint_as_float(w.z & 0xFFFF0000u), wt, a5v);
    a6v = fmaf(__uint_as_float(w.w << 16), wt, a6v);
    a7v = fmaf(__uint_as_float(w.w & 0xFFFF0000u), wt, a7v);
  }
  *(float4*)&red[rw][lane * 8]     = make_float4(a0v, a1v, a2v, a3v);
  *(float4*)&red[rw][lane * 8 + 4] = make_float4(a4v, a5v, a6v, a7v);
  __syncthreads();
  const int h = tid * 2;
  float s0 = red[0][h]     + red[1][h]     + red[2][h]     + red[3][h];
  float s1 = red[0][h + 1] + red[1][h + 1] + red[2][h + 1] + red[3][h + 1];
  float* ob = out + half * 16384 + b * 512 + h;
  atomicAdd(&ob[0], s0);
  atomicAdd(&ob[1], s1);
}

extern "C" void kernel_launch(void* const* d_in, const int* in_sizes, int n_in,
                              void* d_out, int out_size, void* d_ws, size_t ws_size,
                              hipStream_t stream) {
  const void* q  = d_in[0];
  const void* a  = d_in[1];
  const void* U  = d_in[2];
  const void* qm = d_in[3];
  const void* am = d_in[4];
  float* out = (float*)d_out;

  char* ws = (char*)d_ws;
  u16* qb    = (u16*)ws;                       //  33,554,432 B
  u16* ab    = (u16*)(ws + 33554432);          //  33,554,432 B
  u16* qU    = (u16*)(ws + 67108864);          //  33,554,432 B (holds -log2e * qU)
  u16* Ut    = (u16*)(ws + 100663296);         //     524,288 B (dead after gemm<0>)
  float* statsP = (float*)(ws + 100663296);    //   4,194,304 B (overlays Ut; written by gemm<1>)
                                               //   total 104,857,600 B = 100 MiB

  // bf16 host fast path: only U-transpose/zero blocks; no convert blocks anywhere.
  const bool host_bf = (in_sizes[0] == 33554432);
  const int prep_blocks = host_bf ? 64 : 4160;       // 64 + 4096 q-convert
  const int g0_ny       = host_bf ? 256 : 1280;      // 256 GEMM rows + 1024 (=4096 blk) a-convert
  prep_all<<<dim3(prep_blocks), dim3(256), 0, stream>>>(q, a, U, qm, qb, ab, Ut, out);
  // qU[32768x512] = -log2e * ((q|qb) @ Ut^T); extra blocks convert a -> ab (overlapped)
  gemm_bt<0><<<dim3(4, g0_ny, 1), dim3(256), 0, stream>>>(
      qb, Ut, qU, NLOG2E, (size_t)0, (size_t)0, qm, am, statsP,
      (const u16*)q, (const u16*)nullptr, a, ab);
  // per batch: y = qU[b] @ (a|ab)[b]^T = -log2e * X (+pen), fused epilogue, private-slice stats
  gemm_bt<1><<<dim3(8, 8, 32), dim3(256), 0, stream>>>(
      qU, ab, (u16*)nullptr, 1.f, (size_t)524288, (size_t)524288, qm, am, statsP,
      (const u16*)nullptr, (const u16*)a, nullptr, nullptr);
  partial_kernel<<<dim3(8, 64), dim3(256), 0, stream>>>(qb, ab, q, a, qm, statsP, out);
}